// Round 11
// baseline (842.060 us; speedup 1.0000x reference)
//
#include <hip/hip_runtime.h>
#include <stdint.h>
#include <math.h>

#define VV 128000
#define DD 2048
#define BB 32
#define SS 8
#define NCAND 4096

// jax_threefry_partitionable 32-bit stream: counter=(0,flat), bits = o0 ^ o1.  (verified R4+)

// direct global->LDS; dest = wave-uniform base + lane*16, src per-lane (pre-swizzled)
#define GLDS(src, dst) __builtin_amdgcn_global_load_lds( \
    (const __attribute__((address_space(1))) void*)(src), \
    (__attribute__((address_space(3))) void*)(dst), 16, 0, 0)
#define CBAR() asm volatile("" ::: "memory")   // compiler-only ordering fence

// ---------------- threefry2x32 core (key = (0, 42) from jax.random.key(42)) ----------------
__device__ __forceinline__ uint32_t rotl32(uint32_t x, uint32_t r) {
    return (x << r) | (x >> (32u - r));
}

__device__ __forceinline__ void threefry2x32(uint32_t c0, uint32_t c1,
                                             uint32_t& o0, uint32_t& o1) {
    const uint32_t k0 = 0u, k1 = 42u;
    const uint32_t k2 = 0x1BD11BDAu ^ k0 ^ k1;
    uint32_t x0 = c0 + k0;
    uint32_t x1 = c1 + k1;
    #define TF_ROUND(r) { x0 += x1; x1 = rotl32(x1, r); x1 ^= x0; }
    TF_ROUND(13) TF_ROUND(15) TF_ROUND(26) TF_ROUND(6)
    x0 += k1; x1 += k2 + 1u;
    TF_ROUND(17) TF_ROUND(29) TF_ROUND(16) TF_ROUND(24)
    x0 += k2; x1 += k0 + 2u;
    TF_ROUND(13) TF_ROUND(15) TF_ROUND(26) TF_ROUND(6)
    x0 += k0; x1 += k1 + 3u;
    TF_ROUND(17) TF_ROUND(29) TF_ROUND(16) TF_ROUND(24)
    x0 += k1; x1 += k2 + 4u;
    TF_ROUND(13) TF_ROUND(15) TF_ROUND(26) TF_ROUND(6)
    x0 += k2; x1 += k0 + 5u;
    #undef TF_ROUND
    o0 = x0; o1 = x1;
}

__device__ float gumbel_at(uint32_t flat) {
    uint32_t o0, o1;
    threefry2x32(0u, flat, o0, o1);   // counter (hi=0, lo=flat)
    uint32_t bits = o0 ^ o1;          // partitionable 32-bit path
    uint32_t fb = (bits >> 9) | 0x3F800000u;
    float f = __uint_as_float(fb) - 1.0f;
    const float TINY = 1.17549435e-38f;
    float u = (f > 0.0f) ? f : TINY;
    return -logf(-logf(u));
}

__device__ __forceinline__ uint32_t enc_f32(float f) {
    uint32_t u = __float_as_uint(f);
    return u ^ (0x80000000u | (uint32_t)(((int32_t)u) >> 31));  // order-preserving
}

// LDS column swizzle: col = (k_local + rotb(b)) mod 64 -> 2-way banks only
__device__ __forceinline__ int rotb(int b) { return ((b << 2) + ((b >> 3) << 3)) & 63; }

// ---------------- K1: logits = softcap(hs @ emb^T)/temp ----------------
// 512 thr = 8 waves = (row-quad rq 0..3) x (k-half ka 0..1); wave: 4 rows x
// 32 batches x 1024 k. Thread: V_t=4 rows, B_t=8 batches (bl=lane>>4),
// kl=lane&15 k-split; acc[4][8]=32 regs.
// emb: loaded EXACTLY ONCE per block (each (row,k) by one wave). hidden:
// staged EXACTLY ONCE per block into swizzled LDS (wave w stages rows
// (w&3)*8..+7 of half w>>2, 2 GLDS/iter). Double-buffered, raw s_barrier
// (no vmcnt(0) drain), per-wave vmcnt(6) = this iter's 4 e-loads + 2 GLDS.
// e-prefetch depth-1 ping-pong. Per-acc k-order identical to R8-R10;
// kappa partials combined pairwise in epilogue (logits shift ~1e-5).
__global__ __launch_bounds__(512, 2) void gemv_kernel(
    const float* __restrict__ emb, const float* __restrict__ hidden,
    const int* __restrict__ outpos, const float* __restrict__ temps,
    float* __restrict__ out)
{
    __shared__ float hs[2][2][32][64];   // [dbuf][khalf][batch][col] = 64 KB (reused as lpart in epilogue)

    const int tid   = threadIdx.x;
    const int w     = tid >> 6;
    const int lane  = tid & 63;
    const int kl    = lane & 15;
    const int bl    = lane >> 4;       // batch-octet
    const int rq    = w & 3;           // row-quad
    const int ka    = w >> 2;          // k-half
    const int vbase = blockIdx.x * 16;
    const int pos   = outpos[0];

    // staging: wave stages rows rq*8..+7 of k-half ka (A: +bl rows 0..3, B: +4)
    const int srowA = rq * 8 + bl;
    const int srowB = srowA + 4;
    const float* hbase = hidden + (size_t)pos * DD;
    const float* gsA = hbase + (size_t)srowA * (SS * DD) + ka * 1024
                     + (((kl << 2) - rotb(srowA)) & 63);
    const float* gsB = hbase + (size_t)srowB * (SS * DD) + ka * 1024
                     + (((kl << 2) - rotb(srowB)) & 63);

    // compute-side ds_read byte offsets (static-indexed -> registers)
    int ads[8];
    #pragma unroll
    for (int j = 0; j < 8; ++j) {
        int b = bl * 8 + j;
        ads[j] = ka * 8192 + b * 256 + (((kl << 2) + rotb(b)) & 63) * 4;
    }
    char* hsb = (char*)hs;

    // emb row pointers (this thread's 4 rows, its k-half, its kl slot)
    const float* er0 = emb + (size_t)(vbase + rq * 4 + 0) * DD + ka * 1024 + (kl << 2);
    const float* er1 = er0 + DD;
    const float* er2 = er1 + DD;
    const float* er3 = er2 + DD;

    float acc[4][8];
    #pragma unroll
    for (int v = 0; v < 4; ++v)
        #pragma unroll
        for (int j = 0; j < 8; ++j) acc[v][j] = 0.0f;

    // prologue: stage chunk 0 -> slot 0; preload e(0)
    GLDS(gsA, &hs[0][ka][rq * 8][0]);
    GLDS(gsB, &hs[0][ka][rq * 8 + 4][0]);
    CBAR();
    float4 eA0 = *reinterpret_cast<const float4*>(er0);
    float4 eA1 = *reinterpret_cast<const float4*>(er1);
    float4 eA2 = *reinterpret_cast<const float4*>(er2);
    float4 eA3 = *reinterpret_cast<const float4*>(er3);
    float4 eB0, eB1, eB2, eB3;
    CBAR();

    #define FMAQ(V, E, J) \
        acc[V][J] += E.x * h.x; acc[V][J] += E.y * h.y; \
        acc[V][J] += E.z * h.z; acc[V][J] += E.w * h.w;

    #define BODY(J, DB, E0, E1, E2, E3) { \
        const float4 h = *reinterpret_cast<const float4*>(hsb + ads[J] + (DB) * 16384); \
        FMAQ(0, E0, J) FMAQ(1, E1, J) FMAQ(2, E2, J) FMAQ(3, E3, J) }

    // one iteration: prefetch e(S+1), stage chunk S+1 -> slot DB^1, wait own
    // 2-iter-old stage (vmcnt(6)), barrier, 8 swizzled ds_reads + 128 FMAs,
    // barrier (protects slot DB from next iter's stage overwrite).
    #define ITER(S, DB, C0, C1, C2, C3, N0, N1, N2, N3) { \
        const int kn = ((S) + 1) & 15; \
        N0 = *reinterpret_cast<const float4*>(er0 + kn * 64); \
        N1 = *reinterpret_cast<const float4*>(er1 + kn * 64); \
        N2 = *reinterpret_cast<const float4*>(er2 + kn * 64); \
        N3 = *reinterpret_cast<const float4*>(er3 + kn * 64); \
        CBAR(); \
        { const int soff = (((S) < 15) ? (S) + 1 : 15) * 64; \
          GLDS(gsA + soff, &hs[(DB) ^ 1][ka][rq * 8][0]); \
          GLDS(gsB + soff, &hs[(DB) ^ 1][ka][rq * 8 + 4][0]); } \
        asm volatile("s_waitcnt vmcnt(6)" ::: "memory"); \
        __builtin_amdgcn_s_barrier(); \
        CBAR(); \
        BODY(0, DB, C0, C1, C2, C3) BODY(1, DB, C0, C1, C2, C3) \
        BODY(2, DB, C0, C1, C2, C3) BODY(3, DB, C0, C1, C2, C3) \
        BODY(4, DB, C0, C1, C2, C3) BODY(5, DB, C0, C1, C2, C3) \
        BODY(6, DB, C0, C1, C2, C3) BODY(7, DB, C0, C1, C2, C3) \
        CBAR(); \
        __builtin_amdgcn_s_barrier(); \
        CBAR(); \
    }

    #pragma unroll 1
    for (int it = 0; it < 8; ++it) {
        const int s = it * 2;
        ITER(s,     0, eA0, eA1, eA2, eA3, eB0, eB1, eB2, eB3)
        ITER(s + 1, 1, eB0, eB1, eB2, eB3, eA0, eA1, eA2, eA3)
    }
    #undef ITER
    #undef BODY
    #undef FMAQ

    // keep tail prefetch loads alive (uniform vmem count for vmcnt invariant)
    asm volatile("" :: "v"(eA0.x), "v"(eA1.x), "v"(eA2.x), "v"(eA3.x));

    // reduce partial dots across the 16 k-lanes (same tree as R8)
    #pragma unroll
    for (int v = 0; v < 4; ++v)
        #pragma unroll
        for (int j = 0; j < 8; ++j) {
            float a = acc[v][j];
            a += __shfl_xor(a, 1, 64);
            a += __shfl_xor(a, 2, 64);
            a += __shfl_xor(a, 4, 64);
            a += __shfl_xor(a, 8, 64);
            acc[v][j] = a;
        }

    __syncthreads();                    // all hs reads + stray GLDS done (vmcnt0 drain)
    float* lp = (float*)hs;             // lpart[ka][16 rows][33 pad]
    if (kl == 0) {
        #pragma unroll
        for (int v = 0; v < 4; ++v)
            #pragma unroll
            for (int j = 0; j < 8; ++j)
                lp[ka * 528 + (rq * 4 + v) * 33 + (bl * 8 + j)] = acc[v][j];
    }
    __syncthreads();
    {
        const int b2 = tid >> 4;        // batch 0..31
        const int v2 = tid & 15;        // v-row 0..15
        float p = lp[v2 * 33 + b2] + lp[528 + v2 * 33 + b2];
        float l = tanhf(p / 30.0f) * 30.0f;   // final logit softcapping
        l = l / temps[b2];                     // temperature
        out[32 + (size_t)b2 * VV + vbase + v2] = l;
    }
}

// ---------------- K2: per-row top-64 (prob-sorted, stable) + exact-RNG categorical ----------------
__global__ __launch_bounds__(1024) void sample_kernel(
    float* __restrict__ dout, const float* __restrict__ top_ps,
    const int* __restrict__ top_ks)
{
    const int b   = blockIdx.x;
    const int tid = threadIdx.x;
    const float* row = dout + 32 + (size_t)b * VV;

    __shared__ unsigned int hist[2048];            // 8KB
    __shared__ unsigned long long arr[NCAND];      // 32KB: (enc(p)<<32)|~idx
    __shared__ float red[1024];                    // 4KB
    __shared__ float m_sh;
    __shared__ unsigned int thresh_sh;
    __shared__ unsigned int cnt_sh;
    __shared__ float p_arr[64];
    __shared__ unsigned int idx_arr[64];
    __shared__ float S_sh;
    __shared__ unsigned long long keep_sh;

    for (int i = tid; i < 2048; i += 1024) hist[i] = 0u;
    for (int i = tid; i < NCAND; i += 1024) arr[i] = 0ull;
    if (tid == 0) cnt_sh = 0u;
    __syncthreads();

    // ---- pass A: row max + 11-bit float-order histogram ----
    float lmax = -INFINITY;
    for (int i = tid; i < VV; i += 1024) {
        float l = row[i];
        lmax = fmaxf(lmax, l);
        atomicAdd(&hist[enc_f32(l) >> 21], 1u);
    }
    red[tid] = lmax;
    __syncthreads();
    for (int s = 512; s > 0; s >>= 1) {
        if (tid < s) red[tid] = fmaxf(red[tid], red[tid + s]);
        __syncthreads();
    }
    if (tid == 0) {
        float m = red[0];
        m_sh = m;
        int t = (int)(enc_f32(m) >> 21);
        unsigned int cum = 0u;
        for (; t >= 0; --t) { cum += hist[t]; if (cum >= 64u) break; }
        if (t < 0) t = 0;
        thresh_sh = ((unsigned int)t) << 21;
    }
    __syncthreads();
    const float m = m_sh;
    const unsigned int thresh = thresh_sh;

    // ---- pass B: softmax denominator Z ----
    float z = 0.0f;
    for (int i = tid; i < VV; i += 1024) z += expf(row[i] - m);
    red[tid] = z;
    __syncthreads();
    for (int s = 512; s > 0; s >>= 1) {
        if (tid < s) red[tid] += red[tid + s];
        __syncthreads();
    }
    const float Z = red[0];
    __syncthreads();

    // ---- pass C: collect candidates keyed by (prob desc, idx asc) ----
    for (int i = tid; i < VV; i += 1024) {
        float l = row[i];
        if (enc_f32(l) >= thresh) {
            float p = expf(l - m) / Z;
            unsigned int slot = atomicAdd(&cnt_sh, 1u);
            if (slot < NCAND)
                arr[slot] = ((unsigned long long)enc_f32(p) << 32)
                          | (unsigned long long)(~(unsigned int)i);
        }
    }
    __syncthreads();

    // ---- bitonic sort, descending (zeros sink to the end) ----
    for (int k = 2; k <= NCAND; k <<= 1) {
        for (int j = k >> 1; j > 0; j >>= 1) {
            for (int t = tid; t < NCAND; t += 1024) {
                int ixj = t ^ j;
                if (ixj > t) {
                    unsigned long long a = arr[t], c = arr[ixj];
                    bool desc = ((t & k) == 0);
                    if (desc ? (a < c) : (a > c)) { arr[t] = c; arr[ixj] = a; }
                }
            }
            __syncthreads();
        }
    }

    // ---- decode top-64 ----
    if (tid < 64) {
        unsigned long long key = arr[tid];
        p_arr[tid]   = __uint_as_float((unsigned int)(key >> 32) & 0x7FFFFFFFu);
        idx_arr[tid] = ~((unsigned int)(key & 0xFFFFFFFFull));
    }
    __syncthreads();

    // ---- sequential fp32 cumsum + top-p/top-k keep mask (np order) ----
    if (tid == 0) {
        float cum = 0.0f, S = 0.0f;
        unsigned long long keep = 0ull;
        const float tp = top_ps[b];
        const int   tk = top_ks[b];
        for (int r = 0; r < 64; ++r) {
            float p = p_arr[r];
            cum = cum + p;
            float excl = cum - p;
            if (!(excl > tp) && (r < tk)) { keep |= (1ull << r); S = S + p; }
        }
        S_sh = S; keep_sh = keep;
    }
    __syncthreads();

    // ---- gumbel-max over kept set (exact jax.random.categorical(key(42))) ----
    if (tid < 64) {
        unsigned long long pk = 0ull;
        if ((keep_sh >> tid) & 1ull) {
            float q  = p_arr[tid] / S_sh;
            float lp = logf(q);
            unsigned int idx = idx_arr[tid];
            float g = gumbel_at((unsigned int)b * (unsigned int)VV + idx);
            float vf = lp + g;
            pk = ((unsigned long long)enc_f32(vf) << 32)
               | (unsigned long long)(~idx);
        }
        for (int off = 1; off < 64; off <<= 1) {
            unsigned long long o = __shfl_xor(pk, off, 64);
            if (o > pk) pk = o;
        }
        if (tid == 0) {
            unsigned int token = ~((unsigned int)(pk & 0xFFFFFFFFull));
            dout[b] = (float)token;
        }
    }
}

extern "C" void kernel_launch(void* const* d_in, const int* in_sizes, int n_in,
                              void* d_out, int out_size, void* d_ws, size_t ws_size,
                              hipStream_t stream) {
    const float* emb   = (const float*)d_in[0];
    const float* hid   = (const float*)d_in[1];
    const int*   pos   = (const int*)d_in[2];
    const float* temps = (const float*)d_in[3];
    const float* tps   = (const float*)d_in[4];
    const int*   tks   = (const int*)d_in[5];
    float* out = (float*)d_out;

    gemv_kernel<<<dim3(VV / 16), dim3(512), 0, stream>>>(emb, hid, pos, temps, out);
    sample_kernel<<<dim3(BB), dim3(1024), 0, stream>>>(out, tps, tks);
}

// Round 12
// 632.803 us; speedup vs baseline: 1.3307x; 1.3307x over previous
//
#include <hip/hip_runtime.h>
#include <stdint.h>
#include <math.h>

#define VV 128000
#define DD 2048
#define BB 32
#define SS 8
#define NCAND 4096

// jax_threefry_partitionable 32-bit stream: counter=(0,flat), bits = o0 ^ o1.  (verified R4+)

// direct global->LDS; dest = wave-uniform base + lane*16, src per-lane
#define GLDS(src, dst) __builtin_amdgcn_global_load_lds( \
    (const __attribute__((address_space(1))) void*)(src), \
    (__attribute__((address_space(3))) void*)(dst), 16, 0, 0)
#define CBAR() asm volatile("" ::: "memory")   // compiler-only ordering fence

// ---------------- threefry2x32 core (key = (0, 42) from jax.random.key(42)) ----------------
__device__ __forceinline__ uint32_t rotl32(uint32_t x, uint32_t r) {
    return (x << r) | (x >> (32u - r));
}

__device__ __forceinline__ void threefry2x32(uint32_t c0, uint32_t c1,
                                             uint32_t& o0, uint32_t& o1) {
    const uint32_t k0 = 0u, k1 = 42u;
    const uint32_t k2 = 0x1BD11BDAu ^ k0 ^ k1;
    uint32_t x0 = c0 + k0;
    uint32_t x1 = c1 + k1;
    #define TF_ROUND(r) { x0 += x1; x1 = rotl32(x1, r); x1 ^= x0; }
    TF_ROUND(13) TF_ROUND(15) TF_ROUND(26) TF_ROUND(6)
    x0 += k1; x1 += k2 + 1u;
    TF_ROUND(17) TF_ROUND(29) TF_ROUND(16) TF_ROUND(24)
    x0 += k2; x1 += k0 + 2u;
    TF_ROUND(13) TF_ROUND(15) TF_ROUND(26) TF_ROUND(6)
    x0 += k0; x1 += k1 + 3u;
    TF_ROUND(17) TF_ROUND(29) TF_ROUND(16) TF_ROUND(24)
    x0 += k1; x1 += k2 + 4u;
    TF_ROUND(13) TF_ROUND(15) TF_ROUND(26) TF_ROUND(6)
    x0 += k2; x1 += k0 + 5u;
    #undef TF_ROUND
    o0 = x0; o1 = x1;
}

__device__ float gumbel_at(uint32_t flat) {
    uint32_t o0, o1;
    threefry2x32(0u, flat, o0, o1);   // counter (hi=0, lo=flat)
    uint32_t bits = o0 ^ o1;          // partitionable 32-bit path
    uint32_t fb = (bits >> 9) | 0x3F800000u;
    float f = __uint_as_float(fb) - 1.0f;
    const float TINY = 1.17549435e-38f;
    float u = (f > 0.0f) ? f : TINY;
    return -logf(-logf(u));
}

__device__ __forceinline__ uint32_t enc_f32(float f) {
    uint32_t u = __float_as_uint(f);
    return u ^ (0x80000000u | (uint32_t)(((int32_t)u) >> 31));  // order-preserving
}

// ---------------- K1: logits = softcap(hs @ emb^T)/temp ----------------
// 512 thr = 8 waves; block covers 32 v-rows x 32 batches. Wave w owns v-rows
// w*4..w*4+3 -> each emb element loaded by EXACTLY ONE wave (bl-duplicate
// lanes hit the same address -> HW broadcast). hidden staged once per k-phase
// (4 phases x 512 k) into h[32][512] (64 KB) via GLDS; only 2 raw s_barrier
// per phase, NO barriers/waits in the chunk loop (compiler manages e/ds deps).
// Lane: kl=lane&15 (k-split), bl=lane>>4 (batch octet: batches bl*8+j).
// ds_read bank-groups: (addr/16)%8 = kl%8 -> exactly 8 lanes per group =
// uniform = conflict-free. acc[4][8]=32 regs; live ~95 < 128 cap (512,2).
// FMA k-order/reduce/epilogue identical to R8 -> bit-identical tokens.
__global__ __launch_bounds__(512, 2) void gemv_kernel(
    const float* __restrict__ emb, const float* __restrict__ hidden,
    const int* __restrict__ outpos, const float* __restrict__ temps,
    float* __restrict__ out)
{
    __shared__ float h[32][512];       // 64 KB, one k-phase of hidden
    __shared__ float lout[32][33];     // epilogue transpose (4.2 KB)

    const int tid   = threadIdx.x;
    const int w     = tid >> 6;        // wave 0..7
    const int lane  = tid & 63;
    const int kl    = lane & 15;
    const int bl    = lane >> 4;       // batch octet
    const int vbase = blockIdx.x * 32;
    const int pos   = outpos[0];

    const float* hbase = hidden + (size_t)pos * DD;

    // e row pointers: wave w's 4 rows, this lane's kl slot
    const float* er0 = emb + (size_t)(vbase + w * 4 + 0) * DD + (kl << 2);
    const float* er1 = er0 + DD;
    const float* er2 = er1 + DD;
    const float* er3 = er2 + DD;

    // ds_read byte offsets for the 8 batches (add c*256 per chunk)
    int ads[8];
    #pragma unroll
    for (int j = 0; j < 8; ++j) ads[j] = ((bl * 8 + j) * 512 + (kl << 2)) * 4;
    char* hb = (char*)h;

    float acc[4][8];
    #pragma unroll
    for (int v = 0; v < 4; ++v)
        #pragma unroll
        for (int j = 0; j < 8; ++j) acc[v][j] = 0.0f;

    float4 eA0, eA1, eA2, eA3, eB0, eB1, eB2, eB3;

    // staging: per phase, 8 GLDS/thread cover h[32][512] linearly.
    // instr i of wave w writes LDS slots [(i*8+w)*64 .. +64): row b=(i*8+w)>>1,
    // half=(i*8+w)&1 -> global src = hbase + b*SS*DD + p*512 + half*256 + lane*4.
    #define STAGE(P) { \
        _Pragma("unroll") \
        for (int i = 0; i < 8; ++i) { \
            const int x = i * 8 + w; \
            const float* src = hbase + (size_t)(x >> 1) * (SS * DD) \
                             + (P) * 512 + (x & 1) * 256 + (lane << 2); \
            GLDS(src, &h[x >> 1][(x & 1) * 256]); \
        } }

    #define FMAQ(V, E, J) \
        acc[V][J] += E.x * hv.x; acc[V][J] += E.y * hv.y; \
        acc[V][J] += E.z * hv.z; acc[V][J] += E.w * hv.w;

    #define CHUNK(C, C0, C1, C2, C3, N0, N1, N2, N3) { \
        const int np = ((C) < 7) ? p : ((p < 3) ? p + 1 : 3); \
        const int nc = ((C) < 7) ? (C) + 1 : 0; \
        const int no = np * 512 + nc * 64; \
        N0 = *reinterpret_cast<const float4*>(er0 + no); \
        N1 = *reinterpret_cast<const float4*>(er1 + no); \
        N2 = *reinterpret_cast<const float4*>(er2 + no); \
        N3 = *reinterpret_cast<const float4*>(er3 + no); \
        _Pragma("unroll") \
        for (int j = 0; j < 8; ++j) { \
            const float4 hv = *reinterpret_cast<const float4*>(hb + ads[j] + (C) * 256); \
            FMAQ(0, C0, j) FMAQ(1, C1, j) FMAQ(2, C2, j) FMAQ(3, C3, j) \
        } }

    #pragma unroll 1
    for (int p = 0; p < 4; ++p) {
        if (p == 0) {
            STAGE(0)
            CBAR();
            eA0 = *reinterpret_cast<const float4*>(er0);
            eA1 = *reinterpret_cast<const float4*>(er1);
            eA2 = *reinterpret_cast<const float4*>(er2);
            eA3 = *reinterpret_cast<const float4*>(er3);
            CBAR();
            asm volatile("s_waitcnt vmcnt(4)" ::: "memory");  // GLDS retired; e in flight
            __builtin_amdgcn_s_barrier();
        } else {
            __builtin_amdgcn_s_barrier();                     // phase p-1 reads done
            CBAR();
            STAGE(p)
            CBAR();
            asm volatile("s_waitcnt vmcnt(0)" ::: "memory");  // stage done (eA also done)
            __builtin_amdgcn_s_barrier();
        }
        CBAR();
        CHUNK(0, eA0, eA1, eA2, eA3, eB0, eB1, eB2, eB3)
        CHUNK(1, eB0, eB1, eB2, eB3, eA0, eA1, eA2, eA3)
        CHUNK(2, eA0, eA1, eA2, eA3, eB0, eB1, eB2, eB3)
        CHUNK(3, eB0, eB1, eB2, eB3, eA0, eA1, eA2, eA3)
        CHUNK(4, eA0, eA1, eA2, eA3, eB0, eB1, eB2, eB3)
        CHUNK(5, eB0, eB1, eB2, eB3, eA0, eA1, eA2, eA3)
        CHUNK(6, eA0, eA1, eA2, eA3, eB0, eB1, eB2, eB3)
        CHUNK(7, eB0, eB1, eB2, eB3, eA0, eA1, eA2, eA3)
        CBAR();
    }
    #undef CHUNK
    #undef FMAQ
    #undef STAGE

    // keep tail prefetch alive (harmless; avoids mid-loop codegen surprises)
    asm volatile("" :: "v"(eA0.x), "v"(eA1.x), "v"(eA2.x), "v"(eA3.x));

    // reduce partial dots across the 16 k-lanes (identical tree to R8)
    #pragma unroll
    for (int v = 0; v < 4; ++v)
        #pragma unroll
        for (int j = 0; j < 8; ++j) {
            float a = acc[v][j];
            a += __shfl_xor(a, 1, 64);
            a += __shfl_xor(a, 2, 64);
            a += __shfl_xor(a, 4, 64);
            a += __shfl_xor(a, 8, 64);
            acc[v][j] = a;
        }

    __syncthreads();   // full drain before lout reuse patterns
    if (kl == 0) {
        #pragma unroll
        for (int v = 0; v < 4; ++v)
            #pragma unroll
            for (int j = 0; j < 8; ++j) {
                float raw = acc[v][j];
                float l = tanhf(raw / 30.0f) * 30.0f;   // final logit softcapping
                l = l / temps[bl * 8 + j];               // temperature
                lout[w * 4 + v][bl * 8 + j] = l;
            }
    }
    __syncthreads();
    #pragma unroll
    for (int r = 0; r < 2; ++r) {
        const int idx = tid + r * 512;
        const int b2  = idx >> 5;       // batch 0..31
        const int v2  = idx & 31;       // v-row 0..31
        out[32 + (size_t)b2 * VV + vbase + v2] = lout[v2][b2];
    }
}

// ---------------- K2: per-row top-64 (prob-sorted, stable) + exact-RNG categorical ----------------
__global__ __launch_bounds__(1024) void sample_kernel(
    float* __restrict__ dout, const float* __restrict__ top_ps,
    const int* __restrict__ top_ks)
{
    const int b   = blockIdx.x;
    const int tid = threadIdx.x;
    const float* row = dout + 32 + (size_t)b * VV;

    __shared__ unsigned int hist[2048];            // 8KB
    __shared__ unsigned long long arr[NCAND];      // 32KB: (enc(p)<<32)|~idx
    __shared__ float red[1024];                    // 4KB
    __shared__ float m_sh;
    __shared__ unsigned int thresh_sh;
    __shared__ unsigned int cnt_sh;
    __shared__ float p_arr[64];
    __shared__ unsigned int idx_arr[64];
    __shared__ float S_sh;
    __shared__ unsigned long long keep_sh;

    for (int i = tid; i < 2048; i += 1024) hist[i] = 0u;
    for (int i = tid; i < NCAND; i += 1024) arr[i] = 0ull;
    if (tid == 0) cnt_sh = 0u;
    __syncthreads();

    // ---- pass A: row max + 11-bit float-order histogram ----
    float lmax = -INFINITY;
    for (int i = tid; i < VV; i += 1024) {
        float l = row[i];
        lmax = fmaxf(lmax, l);
        atomicAdd(&hist[enc_f32(l) >> 21], 1u);
    }
    red[tid] = lmax;
    __syncthreads();
    for (int s = 512; s > 0; s >>= 1) {
        if (tid < s) red[tid] = fmaxf(red[tid], red[tid + s]);
        __syncthreads();
    }
    if (tid == 0) {
        float m = red[0];
        m_sh = m;
        int t = (int)(enc_f32(m) >> 21);
        unsigned int cum = 0u;
        for (; t >= 0; --t) { cum += hist[t]; if (cum >= 64u) break; }
        if (t < 0) t = 0;
        thresh_sh = ((unsigned int)t) << 21;
    }
    __syncthreads();
    const float m = m_sh;
    const unsigned int thresh = thresh_sh;

    // ---- pass B: softmax denominator Z ----
    float z = 0.0f;
    for (int i = tid; i < VV; i += 1024) z += expf(row[i] - m);
    red[tid] = z;
    __syncthreads();
    for (int s = 512; s > 0; s >>= 1) {
        if (tid < s) red[tid] += red[tid + s];
        __syncthreads();
    }
    const float Z = red[0];
    __syncthreads();

    // ---- pass C: collect candidates keyed by (prob desc, idx asc) ----
    for (int i = tid; i < VV; i += 1024) {
        float l = row[i];
        if (enc_f32(l) >= thresh) {
            float p = expf(l - m) / Z;
            unsigned int slot = atomicAdd(&cnt_sh, 1u);
            if (slot < NCAND)
                arr[slot] = ((unsigned long long)enc_f32(p) << 32)
                          | (unsigned long long)(~(unsigned int)i);
        }
    }
    __syncthreads();

    // ---- bitonic sort, descending (zeros sink to the end) ----
    for (int k = 2; k <= NCAND; k <<= 1) {
        for (int j = k >> 1; j > 0; j >>= 1) {
            for (int t = tid; t < NCAND; t += 1024) {
                int ixj = t ^ j;
                if (ixj > t) {
                    unsigned long long a = arr[t], c = arr[ixj];
                    bool desc = ((t & k) == 0);
                    if (desc ? (a < c) : (a > c)) { arr[t] = c; arr[ixj] = a; }
                }
            }
            __syncthreads();
        }
    }

    // ---- decode top-64 ----
    if (tid < 64) {
        unsigned long long key = arr[tid];
        p_arr[tid]   = __uint_as_float((unsigned int)(key >> 32) & 0x7FFFFFFFu);
        idx_arr[tid] = ~((unsigned int)(key & 0xFFFFFFFFull));
    }
    __syncthreads();

    // ---- sequential fp32 cumsum + top-p/top-k keep mask (np order) ----
    if (tid == 0) {
        float cum = 0.0f, S = 0.0f;
        unsigned long long keep = 0ull;
        const float tp = top_ps[b];
        const int   tk = top_ks[b];
        for (int r = 0; r < 64; ++r) {
            float p = p_arr[r];
            cum = cum + p;
            float excl = cum - p;
            if (!(excl > tp) && (r < tk)) { keep |= (1ull << r); S = S + p; }
        }
        S_sh = S; keep_sh = keep;
    }
    __syncthreads();

    // ---- gumbel-max over kept set (exact jax.random.categorical(key(42))) ----
    if (tid < 64) {
        unsigned long long pk = 0ull;
        if ((keep_sh >> tid) & 1ull) {
            float q  = p_arr[tid] / S_sh;
            float lp = logf(q);
            unsigned int idx = idx_arr[tid];
            float g = gumbel_at((unsigned int)b * (unsigned int)VV + idx);
            float vf = lp + g;
            pk = ((unsigned long long)enc_f32(vf) << 32)
               | (unsigned long long)(~idx);
        }
        for (int off = 1; off < 64; off <<= 1) {
            unsigned long long o = __shfl_xor(pk, off, 64);
            if (o > pk) pk = o;
        }
        if (tid == 0) {
            unsigned int token = ~((unsigned int)(pk & 0xFFFFFFFFull));
            dout[b] = (float)token;
        }
    }
}

extern "C" void kernel_launch(void* const* d_in, const int* in_sizes, int n_in,
                              void* d_out, int out_size, void* d_ws, size_t ws_size,
                              hipStream_t stream) {
    const float* emb   = (const float*)d_in[0];
    const float* hid   = (const float*)d_in[1];
    const int*   pos   = (const int*)d_in[2];
    const float* temps = (const float*)d_in[3];
    const float* tps   = (const float*)d_in[4];
    const int*   tks   = (const int*)d_in[5];
    float* out = (float*)d_out;

    gemv_kernel<<<dim3(VV / 32), dim3(512), 0, stream>>>(emb, hid, pos, temps, out);
    sample_kernel<<<dim3(BB), dim3(1024), 0, stream>>>(out, tps, tks);
}